// Round 9
// baseline (675.240 us; speedup 1.0000x reference)
//
#include <hip/hip_runtime.h>
#include <hip/hip_bf16.h>

// QuantizedSimpleSSM — round 9: batched scalar-W GEMM.
// W (quantized B/C/D, original [n][k] row-major) is read per-wave into SGPRs
// in 8x8 bursts (one lgkm drain per 8-k half, no per-k SMEM/DS entanglement —
// R7's failure mode). X comes from LDS: one ds_read_b128 (mr=4) per lane per k
// feeding 32 FMAs (v_fma v,v,s,v). LDS bytes/FMA = 0.5 -> VALU is the ceiling.
// Block 256 (4 waves, 8-n strip each -> 32-n chunk), X-tile 256 t, grid 1024
// = 4 blocks/CU = 16 waves/CU. Blocks sharing an X-tile (16 n-chunks of one
// (t,b)) are swizzled onto one XCD for L2 X reuse.
// Numerics contract (absmax 0.0 since R2): every output element is one fp32
// FMA chain in strictly ascending k (k0 asc, half asc, k asc); recurrence
// mul-then-add + q8. Unchanged.

#define FULL 512

__device__ __forceinline__ float q8(float x) {
    float xa = fabsf(x);
    float w  = __fadd_rn(xa, 1e-8f);
    int e = (int)((__float_as_uint(w) >> 23) & 0xFFu) - 127;   // floor(log2(w))
    e = e < -7 ? -7 : (e > 7 ? 7 : e);
    float p    = __int_as_float((unsigned)((e + 127) << 23));   // exact 2^e
    float invp = __int_as_float((unsigned)((127 - e) << 23));   // exact 2^-e
    float t  = __fmul_rn(__fsub_rn(__fmul_rn(xa, invp), 1.0f), 8.0f);
    float m  = __fmul_rn(rintf(t), 0.125f);                     // half-to-even
    float r  = __fmul_rn(__fadd_rn(1.0f, m), p);
    return copysignf(r, x);
}

__global__ void quantk(const float* __restrict__ in, float* __restrict__ out, int n) {
    int i = blockIdx.x * blockDim.x + threadIdx.x;
    if (i < n) out[i] = q8(in[i]);
}

// In-place-shape quantization of B, C, D (no transpose needed in this scheme).
__global__ __launch_bounds__(256) void quant3(const float* __restrict__ B,
                                              const float* __restrict__ C,
                                              const float* __restrict__ D,
                                              float* __restrict__ Bq,
                                              float* __restrict__ Cq,
                                              float* __restrict__ Dq) {
    const float* in = blockIdx.z == 0 ? B : (blockIdx.z == 1 ? C : D);
    float* out      = blockIdx.z == 0 ? Bq : (blockIdx.z == 1 ? Cq : Dq);
    int i = blockIdx.x * blockDim.x + threadIdx.x;
    float4 v = *(const float4*)(in + i * 4);
    float4 o;
    o.x = q8(v.x); o.y = q8(v.y); o.z = q8(v.z); o.w = q8(v.w);
    *(float4*)(out + i * 4) = o;
}

// acc[i][n] += sum_k X[k][t0 + lane*4 + i] * Wq[nw0 + n][k], k strictly
// ascending (k0 asc, half asc, k asc). X is [512][512] row-major, Wq is
// [n][k] row-major. nw0 is wave-uniform -> W reads lower to s_load (SGPRs).
// Xs: flat [16*256] floats (16 KB), single-buffered.
__device__ __forceinline__ void gemm_pass_sw(const float* __restrict__ X,
                                             const float* __restrict__ Wq,
                                             int t0, int nw0,
                                             float (&acc)[4][8],
                                             float* __restrict__ Xs,
                                             int tid, int lane) {
    const int srow = tid >> 6;          // wave id 0..3
    const int scol = (tid & 63) * 4;    // lane*4
    const float* wbase = Wq + (size_t)nw0 * FULL;   // uniform
    for (int k0 = 0; k0 < FULL; k0 += 16) {
        float4 st[4];
#pragma unroll
        for (int j = 0; j < 4; ++j)
            st[j] = *(const float4*)(X + (size_t)(k0 + srow + 4 * j) * FULL + t0 + scol);
        __syncthreads();                 // prev compute done reading Xs
#pragma unroll
        for (int j = 0; j < 4; ++j)
            *(float4*)&Xs[(srow + 4 * j) * 256 + scol] = st[j];
        __syncthreads();
#pragma unroll
        for (int h = 0; h < 2; ++h) {
            float w[8][8];               // wave-uniform -> SGPRs
#pragma unroll
            for (int n = 0; n < 8; ++n)
#pragma unroll
                for (int j = 0; j < 8; ++j)
                    w[n][j] = wbase[(size_t)n * FULL + k0 + h * 8 + j];
#pragma unroll
            for (int k = 0; k < 8; ++k) {
                float4 a = *(const float4*)&Xs[(h * 8 + k) * 256 + lane * 4];
#pragma unroll
                for (int n = 0; n < 8; ++n) {
                    acc[0][n] = fmaf(a.x, w[n][k], acc[0][n]);
                    acc[1][n] = fmaf(a.y, w[n][k], acc[1][n]);
                    acc[2][n] = fmaf(a.z, w[n][k], acc[2][n]);
                    acc[3][n] = fmaf(a.w, w[n][k], acc[3][n]);
                }
            }
        }
    }
}

// Decode swizzled 1D block id -> (t0, n-chunk, b). The 16 n-chunks sharing one
// (t,b) X-panel get linear ids with stride 8 -> same XCD (id%8 heuristic),
// so the panel is served from that XCD's L2. Perf heuristic only.
__device__ __forceinline__ void decode_blk(int L, int& t0, int& n0, int& b) {
    int xcd = L & 7, r = L >> 3;
    int nch = r & 15;                   // n-chunk 0..15
    int gix = r >> 4;                   // 0..7
    int g = gix * 8 + xcd;              // 0..63
    t0 = (g & 1) * 256;
    b  = g >> 1;
    n0 = nch * 32;
}

// R'[b][n][t] = sum_d u[b][d][t] * Bq[n][d]. grid 1024, block 256.
__global__ __launch_bounds__(256, 4) void gemm_R(const float* __restrict__ u,
                                                 const float* __restrict__ Bq,
                                                 float* __restrict__ Rp) {
    __shared__ float Xs[16 * 256];
    int t0, n0, b;
    decode_blk(blockIdx.x, t0, n0, b);
    const int tid = threadIdx.x, lane = tid & 63;
    const int nw0 = n0 + __builtin_amdgcn_readfirstlane(tid >> 6) * 8;
    float acc[4][8] = {};
    gemm_pass_sw(u + (size_t)b * (FULL * FULL), Bq, t0, nw0, acc, Xs, tid, lane);
    float* Rb = Rp + (size_t)b * (FULL * FULL);
#pragma unroll
    for (int n = 0; n < 8; ++n) {
        float4 v = make_float4(acc[0][n], acc[1][n], acc[2][n], acc[3][n]);
        *(float4*)(Rb + (size_t)(nw0 + n) * FULL + t0 + lane * 4) = v;
    }
}

// Per-(b,n) recurrence (bitwise np: mul-then-add, q8), pure row scan.
// R'[b][n][t] -> S[b][n][t]. grid (32,4), block 128.
__global__ __launch_bounds__(128) void recur(const float* __restrict__ Rp,
                                             const float* __restrict__ Aq,
                                             float* __restrict__ S) {
    const int b = blockIdx.x;
    const int n = blockIdx.y * 128 + threadIdx.x;
    const float a = Aq[n];
    const float* r = Rp + (size_t)b * (FULL * FULL) + (size_t)n * FULL;
    float* s = S + (size_t)b * (FULL * FULL) + (size_t)n * FULL;
    float st = 0.0f;
    for (int t = 0; t < FULL; t += 4) {
        float4 rv = *(const float4*)(r + t);
        float4 ov;
        st = q8(__fadd_rn(__fmul_rn(st, a), rv.x)); ov.x = st;
        st = q8(__fadd_rn(__fmul_rn(st, a), rv.y)); ov.y = st;
        st = q8(__fadd_rn(__fmul_rn(st, a), rv.z)); ov.z = st;
        st = q8(__fadd_rn(__fmul_rn(st, a), rv.w)); ov.w = st;
        *(float4*)(s + t) = ov;
    }
}

// Y[b][o][t] = q8( (sum_n S[n][t]*Cq[o][n]) + (sum_d u[d][t]*Dq[o][d]) )
// grid 1024, block 256.
__global__ __launch_bounds__(256, 4) void gemm_Y(const float* __restrict__ u,
                                                 const float* __restrict__ S,
                                                 const float* __restrict__ Cq,
                                                 const float* __restrict__ Dq,
                                                 float* __restrict__ Y) {
    __shared__ float Xs[16 * 256];
    int t0, o0, b;
    decode_blk(blockIdx.x, t0, o0, b);
    const int tid = threadIdx.x, lane = tid & 63;
    const int ow0 = o0 + __builtin_amdgcn_readfirstlane(tid >> 6) * 8;
    float c1[4][8] = {};
    gemm_pass_sw(S + (size_t)b * (FULL * FULL), Cq, t0, ow0, c1, Xs, tid, lane);
    float acc[4][8] = {};
    gemm_pass_sw(u + (size_t)b * (FULL * FULL), Dq, t0, ow0, acc, Xs, tid, lane);
    float* Yb = Y + (size_t)b * (FULL * FULL);
#pragma unroll
    for (int n = 0; n < 8; ++n) {
        float4 v;
        v.x = q8(__fadd_rn(c1[0][n], acc[0][n]));
        v.y = q8(__fadd_rn(c1[1][n], acc[1][n]));
        v.z = q8(__fadd_rn(c1[2][n], acc[2][n]));
        v.w = q8(__fadd_rn(c1[3][n], acc[3][n]));
        *(float4*)(Yb + (size_t)(ow0 + n) * FULL + t0 + lane * 4) = v;
    }
}

extern "C" void kernel_launch(void* const* d_in, const int* in_sizes, int n_in,
                              void* d_out, int out_size, void* d_ws, size_t ws_size,
                              hipStream_t stream) {
    const float* u = (const float*)d_in[0];   // (32, 512, 512)
    const float* A = (const float*)d_in[1];   // (512,)
    const float* B = (const float*)d_in[2];   // (512, 512)
    const float* C = (const float*)d_in[3];   // (512, 512)
    const float* D = (const float*)d_in[4];   // (512, 512)

    float* ws = (float*)d_ws;
    float* Aq = ws;                     // 512
    float* Bq = Aq + 512;               // 262144  [n][d]
    float* Cq = Bq + 262144;            // 262144  [o][n]
    float* Dq = Cq + 262144;            // 262144  [o][d]
    float* Rp = Dq + 262144;            // 8388608 [b][n][t]
    float* S  = Rp + 8388608;           // 8388608 [b][n][t]
    float* Y  = (float*)d_out;          // 8388608 [b][o][t]

    quantk<<<2, 256, 0, stream>>>(A, Aq, 512);
    quant3<<<dim3(256, 1, 3), 256, 0, stream>>>(B, C, D, Bq, Cq, Dq);

    gemm_R<<<1024, 256, 0, stream>>>(u, Bq, Rp);
    recur<<<dim3(32, 4), 128, 0, stream>>>(Rp, Aq, S);
    gemm_Y<<<1024, 256, 0, stream>>>(u, S, Cq, Dq, Y);
}

// Round 10
// 515.067 us; speedup vs baseline: 1.3110x; 1.3110x over previous
//
#include <hip/hip_runtime.h>
#include <hip/hip_bf16.h>
#include <hip/hip_fp16.h>

// QuantizedSimpleSSM — round 10: R5 structure + f16 LDS staging for all
// quantized operands. Every q8 value (1+m/8)*2^e, e in [-7,7], is EXACTLY
// representable in f16, so W tiles (Bq/Cq/Dq) and the S state are staged in
// f16 and exactly converted back to fp32 before the FMA -> the per-element
// fp32 ascending-k FMA chain is bitwise unchanged (absmax 0.0 since R2).
// LDS bytes per thread per k: gemm_R / Y-pass2 64->48, Y-pass1 64->32,
// attacking the measured LDS-return-path ceiling (VALUBusy plateau 56-59%).

#define FULL 512

__device__ __forceinline__ float q8(float x) {
    float xa = fabsf(x);
    float w  = __fadd_rn(xa, 1e-8f);
    int e = (int)((__float_as_uint(w) >> 23) & 0xFFu) - 127;   // floor(log2(w))
    e = e < -7 ? -7 : (e > 7 ? 7 : e);
    float p    = __int_as_float((unsigned)((e + 127) << 23));   // exact 2^e
    float invp = __int_as_float((unsigned)((127 - e) << 23));   // exact 2^-e
    float t  = __fmul_rn(__fsub_rn(__fmul_rn(xa, invp), 1.0f), 8.0f);
    float m  = __fmul_rn(rintf(t), 0.125f);                     // half-to-even
    float r  = __fmul_rn(__fadd_rn(1.0f, m), p);
    return copysignf(r, x);
}

__global__ void quantk(const float* __restrict__ in, float* __restrict__ out, int n) {
    int i = blockIdx.x * blockDim.x + threadIdx.x;
    if (i < n) out[i] = q8(in[i]);
}

// out_h[c][r] = (f16)q8(in[r][c]) for three 512x512 matrices (exact cast).
__global__ __launch_bounds__(256) void quantT3h(const float* __restrict__ B,
                                                const float* __restrict__ C,
                                                const float* __restrict__ D,
                                                __half* __restrict__ Bqt,
                                                __half* __restrict__ Cqt,
                                                __half* __restrict__ Dqt) {
    __shared__ float tl[32][33];
    const float* in = blockIdx.z == 0 ? B : (blockIdx.z == 1 ? C : D);
    __half* out     = blockIdx.z == 0 ? Bqt : (blockIdx.z == 1 ? Cqt : Dqt);
    const int r0 = blockIdx.y * 32, c0 = blockIdx.x * 32;
    const int x = threadIdx.x & 31, y = threadIdx.x >> 5;   // 32 x 8
#pragma unroll
    for (int i = 0; i < 32; i += 8)
        tl[y + i][x] = q8(in[(r0 + y + i) * FULL + c0 + x]);
    __syncthreads();
#pragma unroll
    for (int i = 0; i < 32; i += 8)
        out[(c0 + y + i) * FULL + r0 + x] = __float2half(tl[x][y + i]);
}

// ---- pass P1: X fp32, W f16. acc[p][i][q][j] over m = m0+p*64+tx*4+i,
// n = n0+q*64+ty*4+j, k strictly ascending. X [512][512] f32, Wh [512][512] f16
// (both k-major). Xs 8KB, Ws 4KB.
__device__ __forceinline__ void pass_xf_wh(const float* __restrict__ X,
                                           const __half* __restrict__ Wh,
                                           int m0, int n0,
                                           float (&acc)[2][4][2][4],
                                           float (*Xs)[128], __half (*Ws)[128],
                                           int tid) {
    const int tx = tid & 15, ty = tid >> 4;
    const int srow = tid >> 4, sseg4 = (tid & 15) * 4, hseg8 = (tid & 15) * 8;
    const float*  xp = X  + (size_t)srow * FULL + m0 + sseg4;
    const __half* wp = Wh + (size_t)srow * FULL + n0 + hseg8;
    for (int k0 = 0; k0 < FULL; k0 += 16) {
        float4 x0 = *(const float4*)xp;
        float4 x1 = *(const float4*)(xp + 64);
        float4 wv = *(const float4*)wp;          // 8 halves
        xp += 16 * FULL; wp += 16 * FULL;
        __syncthreads();
        *(float4*)&Xs[srow][sseg4]      = x0;
        *(float4*)&Xs[srow][64 + sseg4] = x1;
        *(float4*)&Ws[srow][hseg8]      = wv;
        __syncthreads();
#pragma unroll
        for (int k = 0; k < 16; ++k) {
            float a[2][4];
            *(float4*)&a[0][0] = *(const float4*)&Xs[k][tx * 4];
            *(float4*)&a[1][0] = *(const float4*)&Xs[k][64 + tx * 4];
            __half hb[2][4];
            *(float2*)&hb[0][0] = *(const float2*)&Ws[k][ty * 4];
            *(float2*)&hb[1][0] = *(const float2*)&Ws[k][64 + ty * 4];
            float b[2][4];
#pragma unroll
            for (int q = 0; q < 2; ++q)
#pragma unroll
                for (int j = 0; j < 4; ++j) b[q][j] = __half2float(hb[q][j]);
#pragma unroll
            for (int p = 0; p < 2; ++p)
#pragma unroll
                for (int i = 0; i < 4; ++i)
#pragma unroll
                    for (int q = 0; q < 2; ++q)
#pragma unroll
                        for (int j = 0; j < 4; ++j)
                            acc[p][i][q][j] = fmaf(a[p][i], b[q][j], acc[p][i][q][j]);
        }
    }
}

// ---- pass P2: X f16, W f16 (for Y pass 1: X = S state, exact in f16).
__device__ __forceinline__ void pass_xh_wh(const __half* __restrict__ Xh,
                                           const __half* __restrict__ Wh,
                                           int m0, int n0,
                                           float (&acc)[2][4][2][4],
                                           __half (*Xs)[128], __half (*Ws)[128],
                                           int tid) {
    const int tx = tid & 15, ty = tid >> 4;
    const int srow = tid >> 4, hseg8 = (tid & 15) * 8;
    const __half* xp = Xh + (size_t)srow * FULL + m0 + hseg8;
    const __half* wp = Wh + (size_t)srow * FULL + n0 + hseg8;
    for (int k0 = 0; k0 < FULL; k0 += 16) {
        float4 xv = *(const float4*)xp;          // 8 halves
        float4 wv = *(const float4*)wp;
        xp += 16 * FULL; wp += 16 * FULL;
        __syncthreads();
        *(float4*)&Xs[srow][hseg8] = xv;
        *(float4*)&Ws[srow][hseg8] = wv;
        __syncthreads();
#pragma unroll
        for (int k = 0; k < 16; ++k) {
            __half ha[2][4], hb[2][4];
            *(float2*)&ha[0][0] = *(const float2*)&Xs[k][tx * 4];
            *(float2*)&ha[1][0] = *(const float2*)&Xs[k][64 + tx * 4];
            *(float2*)&hb[0][0] = *(const float2*)&Ws[k][ty * 4];
            *(float2*)&hb[1][0] = *(const float2*)&Ws[k][64 + ty * 4];
            float a[2][4], b[2][4];
#pragma unroll
            for (int p = 0; p < 2; ++p)
#pragma unroll
                for (int i = 0; i < 4; ++i) a[p][i] = __half2float(ha[p][i]);
#pragma unroll
            for (int q = 0; q < 2; ++q)
#pragma unroll
                for (int j = 0; j < 4; ++j) b[q][j] = __half2float(hb[q][j]);
#pragma unroll
            for (int p = 0; p < 2; ++p)
#pragma unroll
                for (int i = 0; i < 4; ++i)
#pragma unroll
                    for (int q = 0; q < 2; ++q)
#pragma unroll
                        for (int j = 0; j < 4; ++j)
                            acc[p][i][q][j] = fmaf(a[p][i], b[q][j], acc[p][i][q][j]);
        }
    }
}

// R'[b][n][t] = sum_d u[b][d][t] * Bqt[d][n]. grid (4,4,32), block 256.
// Stores n-major (Rp[b][n][t]) so the recurrence is a pure row scan.
__global__ __launch_bounds__(256) void gemm_R(const float* __restrict__ u,
                                              const __half* __restrict__ Bqt,
                                              float* __restrict__ Rp) {
    __shared__ float  Xs[16][128];
    __shared__ __half Ws[16][128];
    const int b  = blockIdx.z;
    const int t0 = blockIdx.x * 128, n0 = blockIdx.y * 128;
    const int tid = threadIdx.x;
    const int tx = tid & 15, ty = tid >> 4;
    float acc[2][4][2][4] = {};
    pass_xf_wh(u + (size_t)b * (FULL * FULL), Bqt, t0, n0, acc, Xs, Ws, tid);
    float* Rb = Rp + (size_t)b * (FULL * FULL);
#pragma unroll
    for (int q = 0; q < 2; ++q)
#pragma unroll
        for (int j = 0; j < 4; ++j) {
            const int n = n0 + q * 64 + ty * 4 + j;
#pragma unroll
            for (int p = 0; p < 2; ++p) {
                float4 v = make_float4(acc[p][0][q][j], acc[p][1][q][j],
                                       acc[p][2][q][j], acc[p][3][q][j]);
                *(float4*)(Rb + (size_t)n * FULL + t0 + p * 64 + tx * 4) = v;
            }
        }
}

// Per-(b,n) recurrence (bitwise np: mul-then-add, q8), pure row scan.
// Rp fp32 [b][n][t] -> Sh f16 [b][n][t] (q8 values are exact in f16).
__global__ __launch_bounds__(128) void recur(const float* __restrict__ Rp,
                                             const float* __restrict__ Aq,
                                             __half* __restrict__ Sh) {
    const int b = blockIdx.x;
    const int n = blockIdx.y * 128 + threadIdx.x;
    const float a = Aq[n];
    const float* r = Rp + (size_t)b * (FULL * FULL) + (size_t)n * FULL;
    __half* s = Sh + (size_t)b * (FULL * FULL) + (size_t)n * FULL;
    float st = 0.0f;
    for (int t = 0; t < FULL; t += 4) {
        float4 rv = *(const float4*)(r + t);
        __half h[4];
        st = q8(__fadd_rn(__fmul_rn(st, a), rv.x)); h[0] = __float2half(st);
        st = q8(__fadd_rn(__fmul_rn(st, a), rv.y)); h[1] = __float2half(st);
        st = q8(__fadd_rn(__fmul_rn(st, a), rv.z)); h[2] = __float2half(st);
        st = q8(__fadd_rn(__fmul_rn(st, a), rv.w)); h[3] = __float2half(st);
        *(float2*)(s + t) = *(float2*)h;
    }
}

// Y[b][o][t] = q8( (sum_n S[n][t]*Cqt[n][o]) + (sum_d u[d][t]*Dqt[d][o]) )
// grid (4,4,32), block 256. Pass 1 all-f16 staging, pass 2 X=u fp32.
__global__ __launch_bounds__(256) void gemm_Y(const float* __restrict__ u,
                                              const __half* __restrict__ Sh,
                                              const __half* __restrict__ Cqt,
                                              const __half* __restrict__ Dqt,
                                              float* __restrict__ Y) {
    __shared__ float  Xs[16][128];       // pass2 X; pass1 aliases half tile
    __shared__ __half Ws[16][128];
    const int b  = blockIdx.z;
    const int t0 = blockIdx.x * 128, o0 = blockIdx.y * 128;
    const int tid = threadIdx.x;
    const int tx = tid & 15, ty = tid >> 4;
    float c1[2][4][2][4] = {};
    pass_xh_wh(Sh + (size_t)b * (FULL * FULL), Cqt, t0, o0, c1,
               (__half(*)[128])Xs, Ws, tid);
    float acc[2][4][2][4] = {};
    pass_xf_wh(u + (size_t)b * (FULL * FULL), Dqt, t0, o0, acc, Xs, Ws, tid);

    float* Yb = Y + (size_t)b * (FULL * FULL);
#pragma unroll
    for (int q = 0; q < 2; ++q)
#pragma unroll
        for (int j = 0; j < 4; ++j) {
            float* row = Yb + (size_t)(o0 + q * 64 + ty * 4 + j) * FULL + t0;
#pragma unroll
            for (int p = 0; p < 2; ++p) {
                float y[4];
#pragma unroll
                for (int i = 0; i < 4; ++i)
                    y[i] = q8(__fadd_rn(c1[p][i][q][j], acc[p][i][q][j]));
                *(float4*)(row + p * 64 + tx * 4) = make_float4(y[0], y[1], y[2], y[3]);
            }
        }
}

extern "C" void kernel_launch(void* const* d_in, const int* in_sizes, int n_in,
                              void* d_out, int out_size, void* d_ws, size_t ws_size,
                              hipStream_t stream) {
    const float* u = (const float*)d_in[0];   // (32, 512, 512)
    const float* A = (const float*)d_in[1];   // (512,)
    const float* B = (const float*)d_in[2];   // (512, 512)
    const float* C = (const float*)d_in[3];   // (512, 512)
    const float* D = (const float*)d_in[4];   // (512, 512)

    char* ws = (char*)d_ws;
    float*  Aq  = (float*)ws;                      ws += 512 * 4;
    __half* Bqt = (__half*)ws;                     ws += 262144 * 2;   // [d][n]
    __half* Cqt = (__half*)ws;                     ws += 262144 * 2;   // [n][o]
    __half* Dqt = (__half*)ws;                     ws += 262144 * 2;   // [d][o]
    float*  Rp  = (float*)ws;                      ws += 8388608 * 4;  // [b][n][t]
    __half* Sh  = (__half*)ws;                                         // [b][n][t]
    float*  Y   = (float*)d_out;                                       // [b][o][t]

    quantk<<<2, 256, 0, stream>>>(A, Aq, 512);
    quantT3h<<<dim3(16, 16, 3), 256, 0, stream>>>(B, C, D, Bqt, Cqt, Dqt);

    gemm_R<<<dim3(4, 4, 32), 256, 0, stream>>>(u, Bqt, Rp);
    recur<<<dim3(32, 4), 128, 0, stream>>>(Rp, Aq, Sh);
    gemm_Y<<<dim3(4, 4, 32), 256, 0, stream>>>(u, Sh, Cqt, Dqt, Y);
}